// Round 1
// baseline (354.928 us; speedup 1.0000x reference)
//
#include <hip/hip_runtime.h>

#define STEPS 30
#define HID 32
#define TPB 256
#define LDS_STRIDE (STEPS + 1)   // 31: odd stride -> conflict-free LDS column access

__global__ __launch_bounds__(TPB, 2) void hedge_kernel(
    const float* __restrict__ S,
    const float* __restrict__ W1,
    const float* __restrict__ b1,
    const float* __restrict__ W2,
    const float* __restrict__ b2,
    const float* __restrict__ a_init,
    float* __restrict__ out)
{
    __shared__ float tile[TPB * LDS_STRIDE];   // 31744 B
    const int tid = threadIdx.x;
    const long long base = (long long)blockIdx.x * (TPB * STEPS);

    // ---- Stage S tile (256 rows x 30 cols) coalesced into padded LDS ----
    // Tile is contiguous in global: float2 loads never straddle a row (30 even).
    const float2* __restrict__ S2 = (const float2*)(S + base);
    #pragma unroll
    for (int k = 0; k < (TPB * STEPS) / (2 * TPB); ++k) {   // 15 iters
        int g2 = tid + k * TPB;
        float2 v = S2[g2];
        int g = g2 * 2;
        int row = g / STEPS;
        int col = g - row * STEPS;
        tile[row * LDS_STRIDE + col]     = v.x;
        tile[row * LDS_STRIDE + col + 1] = v.y;
    }

    // ---- Uniform weights into registers ----
    float wa[HID], wc[HID], we[HID], wb[HID], w2v[HID];
    #pragma unroll
    for (int j = 0; j < HID; ++j) {
        wa[j]  = W1[j];            // W1[0][j] : coeff of s
        wc[j]  = W1[HID + j];      // W1[1][j] : coeff of d_prev
        we[j]  = W1[2 * HID + j];  // W1[2][j] : coeff of h
        wb[j]  = b1[j];
        w2v[j] = W2[j];
    }
    const float bias2 = b2[0];
    const float dinit = a_init[0];
    __syncthreads();

    // ---- Recurrence: one thread = one batch element ----
    float h = 0.0f;
    float d = dinit;
    float* my = &tile[tid * LDS_STRIDE];
    #pragma unroll 1   // keep body ~170 instr; 30x full unroll would bloat I-fetch
    for (int t = 0; t < STEPS; ++t) {
        const float s = my[t];
        float a0 = 0.f, a1 = 0.f, a2 = 0.f, a3 = 0.f;   // 4-way reduction tree for ILP
        #pragma unroll
        for (int j = 0; j < HID; j += 4) {
            float t0 = fmaf(wa[j+0], s, fmaf(wc[j+0], d, fmaf(we[j+0], h, wb[j+0])));
            float t1 = fmaf(wa[j+1], s, fmaf(wc[j+1], d, fmaf(we[j+1], h, wb[j+1])));
            float t2 = fmaf(wa[j+2], s, fmaf(wc[j+2], d, fmaf(we[j+2], h, wb[j+2])));
            float t3 = fmaf(wa[j+3], s, fmaf(wc[j+3], d, fmaf(we[j+3], h, wb[j+3])));
            a0 = fmaf(fmaxf(t0, 0.f), w2v[j+0], a0);
            a1 = fmaf(fmaxf(t1, 0.f), w2v[j+1], a1);
            a2 = fmaf(fmaxf(t2, 0.f), w2v[j+2], a2);
            a3 = fmaf(fmaxf(t3, 0.f), w2v[j+3], a3);
        }
        const float dn = bias2 + ((a0 + a1) + (a2 + a3));
        h = fmaf(0.2f, dn, 0.8f * h);    // h_new = 0.8*h + 0.2*d
        d = dn;
        my[t] = dn;    // S[t] consumed this step -> reuse slot for output d_t
    }
    __syncthreads();

    // ---- Dump outputs coalesced (same layout as S) ----
    float2* __restrict__ O2 = (float2*)(out + base);
    #pragma unroll
    for (int k = 0; k < (TPB * STEPS) / (2 * TPB); ++k) {   // 15 iters
        int g2 = tid + k * TPB;
        int g = g2 * 2;
        int row = g / STEPS;
        int col = g - row * STEPS;
        float2 v;
        v.x = tile[row * LDS_STRIDE + col];
        v.y = tile[row * LDS_STRIDE + col + 1];
        O2[g2] = v;
    }
}

extern "C" void kernel_launch(void* const* d_in, const int* in_sizes, int n_in,
                              void* d_out, int out_size, void* d_ws, size_t ws_size,
                              hipStream_t stream) {
    const float* S      = (const float*)d_in[0];
    const float* W1     = (const float*)d_in[1];
    const float* b1     = (const float*)d_in[2];
    const float* W2     = (const float*)d_in[3];
    const float* b2     = (const float*)d_in[4];
    const float* a_init = (const float*)d_in[5];
    float* out = (float*)d_out;

    const int batch = in_sizes[0] / STEPS;        // 1048576
    const int grid  = batch / TPB;                // 4096 (batch is an exact multiple of 256)
    hedge_kernel<<<grid, TPB, 0, stream>>>(S, W1, b1, W2, b2, a_init, out);
}

// Round 2
// 270.691 us; speedup vs baseline: 1.3112x; 1.3112x over previous
//
#include <hip/hip_runtime.h>

#define STEPS 30
#define HID 32
#define HALF_H 16
#define TPB 256
#define EPB (TPB / 2)            // 128 elements per block (2 lanes per element)
#define LDS_STRIDE (STEPS + 1)   // 31: odd stride -> conflict-free per-element column reads

__global__ __launch_bounds__(TPB, 4) void hedge_kernel(
    const float* __restrict__ S,
    const float* __restrict__ W1,
    const float* __restrict__ b1,
    const float* __restrict__ W2,
    const float* __restrict__ b2,
    const float* __restrict__ a_init,
    float* __restrict__ out)
{
    __shared__ float tile[EPB * LDS_STRIDE];   // 128*31*4 = 15872 B
    const int tid  = threadIdx.x;
    const int half = tid & 1;                  // which 16 hidden units this lane owns
    const int el   = tid >> 1;                 // local element index [0,128)
    const long long base = (long long)blockIdx.x * (EPB * STEPS);

    // ---- Stage S tile (128 elems x 30 steps, 3840 floats) coalesced into padded LDS ----
    #pragma unroll
    for (int k = 0; k < (EPB * STEPS) / TPB; ++k) {   // 15 iters
        int idx = tid + k * TPB;
        float v = S[base + idx];
        int row = idx / STEPS;
        int col = idx - row * STEPS;
        tile[row * LDS_STRIDE + col] = v;
    }

    // ---- Per-lane weight slice into VGPRs (lane-dependent address => vector regs) ----
    const int j0 = half * HALF_H;
    float wa[HALF_H], wc[HALF_H], we[HALF_H], wb[HALF_H], w2[HALF_H];
    #pragma unroll
    for (int q = 0; q < HALF_H / 4; ++q) {
        float4 va = ((const float4*)(W1 + 0 * HID + j0))[q];  // coeff of s
        float4 vc = ((const float4*)(W1 + 1 * HID + j0))[q];  // coeff of d_prev
        float4 ve = ((const float4*)(W1 + 2 * HID + j0))[q];  // coeff of h
        float4 vb = ((const float4*)(b1 + j0))[q];
        float4 v2 = ((const float4*)(W2 + j0))[q];
        wa[4*q+0]=va.x; wa[4*q+1]=va.y; wa[4*q+2]=va.z; wa[4*q+3]=va.w;
        wc[4*q+0]=vc.x; wc[4*q+1]=vc.y; wc[4*q+2]=vc.z; wc[4*q+3]=vc.w;
        we[4*q+0]=ve.x; we[4*q+1]=ve.y; we[4*q+2]=ve.z; we[4*q+3]=ve.w;
        wb[4*q+0]=vb.x; wb[4*q+1]=vb.y; wb[4*q+2]=vb.z; wb[4*q+3]=vb.w;
        w2[4*q+0]=v2.x; w2[4*q+1]=v2.y; w2[4*q+2]=v2.z; w2[4*q+3]=v2.w;
    }
    const float bias2 = b2[0];
    float d = a_init[0];
    float h = 0.0f;
    __syncthreads();

    // ---- Recurrence: lane pair (2k, 2k+1) = one element; 16 hidden units per lane ----
    float* my = &tile[el * LDS_STRIDE];
    #pragma unroll
    for (int t = 0; t < STEPS; ++t) {
        const float s = my[t];                 // both lanes read same addr: LDS broadcast
        float a0 = 0.f, a1 = 0.f, a2 = 0.f, a3 = 0.f;
        #pragma unroll
        for (int j = 0; j < HALF_H; j += 4) {
            float t0 = fmaf(wa[j+0], s, fmaf(wc[j+0], d, fmaf(we[j+0], h, wb[j+0])));
            float t1 = fmaf(wa[j+1], s, fmaf(wc[j+1], d, fmaf(we[j+1], h, wb[j+1])));
            float t2 = fmaf(wa[j+2], s, fmaf(wc[j+2], d, fmaf(we[j+2], h, wb[j+2])));
            float t3 = fmaf(wa[j+3], s, fmaf(wc[j+3], d, fmaf(we[j+3], h, wb[j+3])));
            a0 = fmaf(fmaxf(t0, 0.f), w2[j+0], a0);
            a1 = fmaf(fmaxf(t1, 0.f), w2[j+1], a1);
            a2 = fmaf(fmaxf(t2, 0.f), w2[j+2], a2);
            a3 = fmaf(fmaxf(t3, 0.f), w2[j+3], a3);
        }
        float acc = (a0 + a1) + (a2 + a3);
        acc += __shfl_xor(acc, 1, 64);         // combine the two 16-unit halves
        const float dn = bias2 + acc;          // both lanes hold full d_t
        h = fmaf(0.2f, dn, 0.8f * h);
        d = dn;
        if (!half) my[t] = dn;                 // S[t] consumed; slot reused for output
    }
    __syncthreads();

    // ---- Dump outputs coalesced (same flat layout as S) ----
    #pragma unroll
    for (int k = 0; k < (EPB * STEPS) / TPB; ++k) {   // 15 iters
        int idx = tid + k * TPB;
        int row = idx / STEPS;
        int col = idx - row * STEPS;
        out[base + idx] = tile[row * LDS_STRIDE + col];
    }
}

extern "C" void kernel_launch(void* const* d_in, const int* in_sizes, int n_in,
                              void* d_out, int out_size, void* d_ws, size_t ws_size,
                              hipStream_t stream) {
    const float* S      = (const float*)d_in[0];
    const float* W1     = (const float*)d_in[1];
    const float* b1     = (const float*)d_in[2];
    const float* W2     = (const float*)d_in[3];
    const float* b2     = (const float*)d_in[4];
    const float* a_init = (const float*)d_in[5];
    float* out = (float*)d_out;

    const int batch = in_sizes[0] / STEPS;    // 1048576
    const int grid  = batch / EPB;            // 8192 blocks of 128 elements
    hedge_kernel<<<grid, TPB, 0, stream>>>(S, W1, b1, W2, b2, a_init, out);
}